// Round 2
// baseline (1491.063 us; speedup 1.0000x reference)
//
#include <hip/hip_runtime.h>

namespace {

constexpr int BATCH = 4096;
constexpr int DIN   = 2048;
constexpr int HID   = 1024;
constexpr int NEMB  = 1024;
constexpr int EDIM  = 8;
constexpr float LN_EPS = 1e-5f;
constexpr float BETA   = 0.001f;

// ---------------- GEMM fp32: C = A[M,K] @ B[K,N] + bias[N] ----------------
// 128x128 tile, BK=16, 256 threads, 8x8 micro-tile/thread.
// Numerics: per-k-tile partial accumulators cut the sequential fp32 chain
// from K (2048) to ~K/BK + BK (~144) -> ~14x lower accumulation noise.
// This matters: argmin flips downstream are driven by z-noise.
__global__ __launch_bounds__(256) void gemm_bias_f32(
    const float* __restrict__ A, const float* __restrict__ B,
    const float* __restrict__ bias, float* __restrict__ C,
    int M, int N, int K)
{
  constexpr int BM = 128, BN = 128, BK = 16;
  __shared__ float As[BK][BM + 4];   // [k][m], +4 pad
  __shared__ float Bs[BK][BN];       // [k][n]
  const int t  = threadIdx.x;
  const int tx = t & 15, ty = t >> 4;
  const int bm = blockIdx.y * BM, bn = blockIdx.x * BN;

  const int a_m = t >> 1, a_k = (t & 1) << 3;
  const int b_k = t >> 4, b_n = (t & 15) << 3;

  const float* Ap = A + (size_t)(bm + a_m) * K + a_k;
  const float* Bp = B + (size_t)b_k * N + (bn + b_n);

  float acc[8][8] = {};

  for (int k0 = 0; k0 < K; k0 += BK) {
    float4 av0 = *(const float4*)(Ap + k0);
    float4 av1 = *(const float4*)(Ap + k0 + 4);
    float4 bv0 = *(const float4*)(Bp + (size_t)k0 * N);
    float4 bv1 = *(const float4*)(Bp + (size_t)k0 * N + 4);
    __syncthreads();   // previous iteration's LDS reads complete
    As[a_k + 0][a_m] = av0.x;
    As[a_k + 1][a_m] = av0.y;
    As[a_k + 2][a_m] = av0.z;
    As[a_k + 3][a_m] = av0.w;
    As[a_k + 4][a_m] = av1.x;
    As[a_k + 5][a_m] = av1.y;
    As[a_k + 6][a_m] = av1.z;
    As[a_k + 7][a_m] = av1.w;
    *(float4*)&Bs[b_k][b_n]     = bv0;
    *(float4*)&Bs[b_k][b_n + 4] = bv1;
    __syncthreads();

    float part[8][8] = {};   // fresh per-tile partial accumulator
#pragma unroll
    for (int k = 0; k < BK; ++k) {
      float a[8], b[8];
      *(float4*)(a)     = *(const float4*)&As[k][ty * 8];
      *(float4*)(a + 4) = *(const float4*)&As[k][ty * 8 + 4];
      *(float4*)(b)     = *(const float4*)&Bs[k][tx * 8];
      *(float4*)(b + 4) = *(const float4*)&Bs[k][tx * 8 + 4];
#pragma unroll
      for (int i = 0; i < 8; ++i)
#pragma unroll
        for (int j = 0; j < 8; ++j)
          part[i][j] = fmaf(a[i], b[j], part[i][j]);
    }
#pragma unroll
    for (int i = 0; i < 8; ++i)
#pragma unroll
      for (int j = 0; j < 8; ++j)
        acc[i][j] += part[i][j];
  }

  float bsv[8];
  *(float4*)(bsv)     = *(const float4*)(bias + bn + tx * 8);
  *(float4*)(bsv + 4) = *(const float4*)(bias + bn + tx * 8 + 4);
#pragma unroll
  for (int i = 0; i < 8; ++i) {
    float* Cr = C + (size_t)(bm + ty * 8 + i) * N + bn + tx * 8;
    float4 v0 = { acc[i][0] + bsv[0], acc[i][1] + bsv[1],
                  acc[i][2] + bsv[2], acc[i][3] + bsv[3] };
    float4 v1 = { acc[i][4] + bsv[4], acc[i][5] + bsv[5],
                  acc[i][6] + bsv[6], acc[i][7] + bsv[7] };
    *(float4*)(Cr)     = v0;
    *(float4*)(Cr + 4) = v1;
  }
}

// ---------------- LayerNorm (+optional ReLU), one block per row of 1024 ----
template<bool RELU>
__global__ __launch_bounds__(256) void ln_act(
    const float* __restrict__ X, float* __restrict__ Y,
    const float* __restrict__ g, const float* __restrict__ be)
{
  const int t = threadIdx.x;
  const size_t base = (size_t)blockIdx.x * HID + t * 4;
  float4 v = *(const float4*)(X + base);
  float s = v.x + v.y + v.z + v.w;
  float q = v.x * v.x + v.y * v.y + v.z * v.z + v.w * v.w;
#pragma unroll
  for (int off = 32; off > 0; off >>= 1) {
    s += __shfl_down(s, off);
    q += __shfl_down(q, off);
  }
  __shared__ float ls[4], lq[4];
  if ((t & 63) == 0) { ls[t >> 6] = s; lq[t >> 6] = q; }
  __syncthreads();
  s = ls[0] + ls[1] + ls[2] + ls[3];
  q = lq[0] + lq[1] + lq[2] + lq[3];
  const float mean = s * (1.0f / HID);
  const float var  = q * (1.0f / HID) - mean * mean;
  const float rstd = rsqrtf(var + LN_EPS);
  float4 gv = *(const float4*)(g + t * 4);
  float4 bv = *(const float4*)(be + t * 4);
  float4 o;
  o.x = (v.x - mean) * rstd * gv.x + bv.x;
  o.y = (v.y - mean) * rstd * gv.y + bv.y;
  o.z = (v.z - mean) * rstd * gv.z + bv.z;
  o.w = (v.w - mean) * rstd * gv.w + bv.w;
  if (RELU) {
    o.x = fmaxf(o.x, 0.0f); o.y = fmaxf(o.y, 0.0f);
    o.z = fmaxf(o.z, 0.0f); o.w = fmaxf(o.w, 0.0f);
  }
  *(float4*)(Y + base) = o;
}

// ---------------- VQ: argmin over codebook, in-place relu(z_q), loss partials
// Pass A: fp32 two-best scan with score 0.5|e|^2 - z.e (monotone in |z-e|^2).
// If the top-2 gap is inside the fp32 score-noise margin, rescan that row in
// fp64 with the direct |z-e|^2 formula (rare path).
__global__ __launch_bounds__(256) void vq_kernel(
    const float* __restrict__ Z, const float* __restrict__ CB,
    float* __restrict__ ZQ, float* __restrict__ partial)
{
  __shared__ float e[NEMB][EDIM];   // 32 KB
  __shared__ float qn[NEMB];        // 4 KB : 0.5*|e|^2
  const int t = threadIdx.x;
  for (int i = t; i < NEMB * EDIM / 4; i += 256)
    ((float4*)&e[0][0])[i] = ((const float4*)CB)[i];
  __syncthreads();
  for (int i = t; i < NEMB; i += 256) {
    float s = 0.0f;
#pragma unroll
    for (int j = 0; j < EDIM; ++j) s += e[i][j] * e[i][j];
    qn[i] = 0.5f * s;
  }
  __syncthreads();

  const size_t sv = (size_t)blockIdx.x * 256 + t;   // subvector id
  const float* zp = Z + sv * EDIM;
  float z0[EDIM];
  *(float4*)(z0)     = *(const float4*)(zp);
  *(float4*)(z0 + 4) = *(const float4*)(zp + 4);

  float b1 = 1e30f, b2 = 1e30f;
  int bidx = 0;
  for (int i = 0; i < NEMB; ++i) {
    float d = qn[i];
#pragma unroll
    for (int j = 0; j < EDIM; ++j) d = fmaf(-z0[j], e[i][j], d);
    if (d < b1) { b2 = b1; b1 = d; bidx = i; }
    else if (d < b2) { b2 = d; }
  }

  if (b2 - b1 < 1e-4f) {            // near-tie: resolve in fp64 (rare)
    double bd = 1e300;
    int ii = 0;
    for (int i = 0; i < NEMB; ++i) {
      double d = 0.0;
#pragma unroll
      for (int j = 0; j < EDIM; ++j) {
        double diff = (double)z0[j] - (double)e[i][j];
        d += diff * diff;
      }
      if (d < bd) { bd = d; ii = i; }
    }
    bidx = ii;
  }

  // loss contribution |z - e_best|^2 in fp64
  double lsq = 0.0;
#pragma unroll
  for (int j = 0; j < EDIM; ++j) {
    double diff = (double)z0[j] - (double)e[bidx][j];
    lsq += diff * diff;
  }

  float o[EDIM];
#pragma unroll
  for (int j = 0; j < EDIM; ++j) o[j] = fmaxf(e[bidx][j], 0.0f);  // relu(z_q)
  float* op = ZQ + sv * EDIM;
  *(float4*)(op)     = *(const float4*)(o);
  *(float4*)(op + 4) = *(const float4*)(o + 4);

  double dm = lsq;
#pragma unroll
  for (int off = 32; off > 0; off >>= 1) dm += __shfl_down(dm, off);
  __shared__ double lsum[4];
  if ((t & 63) == 0) lsum[t >> 6] = dm;
  __syncthreads();
  if (t == 0) partial[blockIdx.x] = (float)(lsum[0] + lsum[1] + lsum[2] + lsum[3]);
}

__global__ __launch_bounds__(256) void loss_finalize(
    const float* __restrict__ partial, float* __restrict__ out)
{
  const int t = threadIdx.x;
  double s = 0.0;
  for (int i = t; i < 2048; i += 256) s += (double)partial[i];
#pragma unroll
  for (int off = 32; off > 0; off >>= 1) s += __shfl_down(s, off);
  __shared__ double ls[4];
  if ((t & 63) == 0) ls[t >> 6] = s;
  __syncthreads();
  if (t == 0) {
    double total = ls[0] + ls[1] + ls[2] + ls[3];
    out[0] = (float)(total * (1.0 + (double)BETA) / (double)((size_t)BATCH * HID));
  }
}

} // namespace

extern "C" void kernel_launch(void* const* d_in, const int* in_sizes, int n_in,
                              void* d_out, int out_size, void* d_ws, size_t ws_size,
                              hipStream_t stream)
{
  const float* x   = (const float*)d_in[0];
  const float* cb  = (const float*)d_in[1];
  const float* W0  = (const float*)d_in[2];
  const float* b0  = (const float*)d_in[3];
  const float* g0  = (const float*)d_in[4];
  const float* be0 = (const float*)d_in[5];
  const float* W1  = (const float*)d_in[6];
  const float* b1  = (const float*)d_in[7];
  const float* g1  = (const float*)d_in[8];
  const float* be1 = (const float*)d_in[9];
  const float* W2  = (const float*)d_in[10];
  const float* b2  = (const float*)d_in[11];
  const float* g2  = (const float*)d_in[12];
  const float* be2 = (const float*)d_in[13];
  const float* W3  = (const float*)d_in[14];
  const float* b3  = (const float*)d_in[15];
  const float* g3  = (const float*)d_in[16];
  const float* be3 = (const float*)d_in[17];
  const float* W4  = (const float*)d_in[18];
  const float* b4  = (const float*)d_in[19];
  const float* g4  = (const float*)d_in[20];
  const float* be4 = (const float*)d_in[21];
  const float* W5  = (const float*)d_in[22];
  const float* b5  = (const float*)d_in[23];
  float* out = (float*)d_out;

  char* ws = (char*)d_ws;
  float* P = (float*)ws;                                         // 16 MB
  float* Q = (float*)(ws + (size_t)BATCH * HID * sizeof(float)); // 16 MB
  float* partial = (float*)(ws + (size_t)2 * BATCH * HID * sizeof(float)); // 8 KB

  dim3 blk(256);
  dim3 gH(HID / 128, BATCH / 128);
  dim3 gO(DIN / 128, BATCH / 128);

  // encoder
  gemm_bias_f32<<<gH, blk, 0, stream>>>(x, W0, b0, P, BATCH, HID, DIN);
  ln_act<true><<<dim3(BATCH), blk, 0, stream>>>(P, Q, g0, be0);
  gemm_bias_f32<<<gH, blk, 0, stream>>>(Q, W1, b1, P, BATCH, HID, HID);
  ln_act<true><<<dim3(BATCH), blk, 0, stream>>>(P, Q, g1, be1);
  gemm_bias_f32<<<gH, blk, 0, stream>>>(Q, W2, b2, P, BATCH, HID, HID);
  ln_act<false><<<dim3(BATCH), blk, 0, stream>>>(P, Q, g2, be2);  // Q = z

  // vector quantize (in-place: Q becomes relu(z_q)), loss partials
  vq_kernel<<<dim3(BATCH * HID / EDIM / 256), blk, 0, stream>>>(Q, cb, Q, partial);

  // decoder
  gemm_bias_f32<<<gH, blk, 0, stream>>>(Q, W3, b3, P, BATCH, HID, HID);
  ln_act<true><<<dim3(BATCH), blk, 0, stream>>>(P, Q, g3, be3);
  gemm_bias_f32<<<gH, blk, 0, stream>>>(Q, W4, b4, P, BATCH, HID, HID);
  ln_act<true><<<dim3(BATCH), blk, 0, stream>>>(P, Q, g4, be4);
  gemm_bias_f32<<<gO, blk, 0, stream>>>(Q, W5, b5, out, BATCH, DIN, HID);

  loss_finalize<<<dim3(1), blk, 0, stream>>>(partial, out + (size_t)BATCH * DIN);
}

// Round 3
// 1150.426 us; speedup vs baseline: 1.2961x; 1.2961x over previous
//
#include <hip/hip_runtime.h>

namespace {

constexpr int BATCH = 4096;
constexpr int DIN   = 2048;
constexpr int HID   = 1024;
constexpr int NEMB  = 1024;
constexpr int EDIM  = 8;
constexpr float LN_EPS = 1e-5f;
constexpr float BETA   = 0.001f;

typedef __attribute__((ext_vector_type(8))) short bf16x8;
typedef __attribute__((ext_vector_type(4))) float f32x4;

__device__ inline unsigned short f2bf(float f) {
  unsigned int x = __float_as_uint(f);
  x += 0x7FFFu + ((x >> 16) & 1u);      // round-to-nearest-even
  return (unsigned short)(x >> 16);
}

// ---------------- GEMM fp32 (encoder) — unchanged from R2 (passed) --------
__global__ __launch_bounds__(256) void gemm_bias_f32(
    const float* __restrict__ A, const float* __restrict__ B,
    const float* __restrict__ bias, float* __restrict__ C,
    int M, int N, int K)
{
  constexpr int BM = 128, BN = 128, BK = 16;
  __shared__ float As[BK][BM + 4];
  __shared__ float Bs[BK][BN];
  const int t  = threadIdx.x;
  const int tx = t & 15, ty = t >> 4;
  const int bm = blockIdx.y * BM, bn = blockIdx.x * BN;

  const int a_m = t >> 1, a_k = (t & 1) << 3;
  const int b_k = t >> 4, b_n = (t & 15) << 3;

  const float* Ap = A + (size_t)(bm + a_m) * K + a_k;
  const float* Bp = B + (size_t)b_k * N + (bn + b_n);

  float acc[8][8] = {};

  for (int k0 = 0; k0 < K; k0 += BK) {
    float4 av0 = *(const float4*)(Ap + k0);
    float4 av1 = *(const float4*)(Ap + k0 + 4);
    float4 bv0 = *(const float4*)(Bp + (size_t)k0 * N);
    float4 bv1 = *(const float4*)(Bp + (size_t)k0 * N + 4);
    __syncthreads();
    As[a_k + 0][a_m] = av0.x;
    As[a_k + 1][a_m] = av0.y;
    As[a_k + 2][a_m] = av0.z;
    As[a_k + 3][a_m] = av0.w;
    As[a_k + 4][a_m] = av1.x;
    As[a_k + 5][a_m] = av1.y;
    As[a_k + 6][a_m] = av1.z;
    As[a_k + 7][a_m] = av1.w;
    *(float4*)&Bs[b_k][b_n]     = bv0;
    *(float4*)&Bs[b_k][b_n + 4] = bv1;
    __syncthreads();

    float part[8][8] = {};
#pragma unroll
    for (int k = 0; k < BK; ++k) {
      float a[8], b[8];
      *(float4*)(a)     = *(const float4*)&As[k][ty * 8];
      *(float4*)(a + 4) = *(const float4*)&As[k][ty * 8 + 4];
      *(float4*)(b)     = *(const float4*)&Bs[k][tx * 8];
      *(float4*)(b + 4) = *(const float4*)&Bs[k][tx * 8 + 4];
#pragma unroll
      for (int i = 0; i < 8; ++i)
#pragma unroll
        for (int j = 0; j < 8; ++j)
          part[i][j] = fmaf(a[i], b[j], part[i][j]);
    }
#pragma unroll
    for (int i = 0; i < 8; ++i)
#pragma unroll
      for (int j = 0; j < 8; ++j)
        acc[i][j] += part[i][j];
  }

  float bsv[8];
  *(float4*)(bsv)     = *(const float4*)(bias + bn + tx * 8);
  *(float4*)(bsv + 4) = *(const float4*)(bias + bn + tx * 8 + 4);
#pragma unroll
  for (int i = 0; i < 8; ++i) {
    float* Cr = C + (size_t)(bm + ty * 8 + i) * N + bn + tx * 8;
    float4 v0 = { acc[i][0] + bsv[0], acc[i][1] + bsv[1],
                  acc[i][2] + bsv[2], acc[i][3] + bsv[3] };
    float4 v1 = { acc[i][4] + bsv[4], acc[i][5] + bsv[5],
                  acc[i][6] + bsv[6], acc[i][7] + bsv[7] };
    *(float4*)(Cr)     = v0;
    *(float4*)(Cr + 4) = v1;
  }
}

// ---------------- weight convert + transpose: Wt[N][K] bf16 = W[K][N] f32 --
__global__ __launch_bounds__(256) void conv_w_bf16t(
    const float* __restrict__ W, unsigned short* __restrict__ Wt, int K, int N)
{
  __shared__ float tile[32][33];
  const int tx = threadIdx.x & 31, ty = threadIdx.x >> 5;   // 32x8
  const int n0 = blockIdx.x * 32, k0 = blockIdx.y * 32;
#pragma unroll
  for (int r = ty; r < 32; r += 8)
    tile[r][tx] = W[(size_t)(k0 + r) * N + n0 + tx];
  __syncthreads();
#pragma unroll
  for (int r = ty; r < 32; r += 8)
    Wt[(size_t)(n0 + r) * K + k0 + tx] = f2bf(tile[tx][r]);
}

// ---------------- GEMM bf16 MFMA (decoder): C = A @ Wt^T + bias -----------
// A [M][K] bf16, Bt [N][K] bf16. 128x128 tile, BK=64, 4 waves, 16x16x32 MFMA.
// Both operands identical LDS addressing (row-major [outer][k], XOR-swizzled:
// byte ^= (row&7)<<4 -> 2-way max on ds_read_b128). Reg-staged, single LDS
// buffer, 2 barriers/iter, next-tile global loads issued before compute.
__global__ __launch_bounds__(256) void gemm_bf16_mfma(
    const unsigned short* __restrict__ A, const unsigned short* __restrict__ Bt,
    const float* __restrict__ bias, float* __restrict__ C,
    int M, int N, int K)
{
  constexpr int BM = 128, BK = 64;
  __shared__ unsigned short lds[2 * BM * BK];   // A tile then B tile, 32 KB
  const int t    = threadIdx.x;
  const int lane = t & 63, w = t >> 6;
  const int wr = w >> 1, wc = w & 1;
  const int m0 = blockIdx.y * BM, n0 = blockIdx.x * BM;
  const int NT = K / BK;

  // staging: 4 chunks of 16B per tile per thread; chunk c = i*256 + t
  const int srow = t >> 3;          // 8 chunks per 128B row
  const int sj   = t & 7;
  const unsigned short* Ag = A  + (size_t)(m0 + srow) * K + sj * 8;
  const unsigned short* Bg = Bt + (size_t)(n0 + srow) * K + sj * 8;
  int ldsoff[4];
#pragma unroll
  for (int i = 0; i < 4; ++i) {
    int row  = srow + i * 32;
    int byte = row * 128 + sj * 16;
    ldsoff[i] = byte ^ ((row & 7) << 4);
  }

  uint4 ra[4], rb[4];
  auto GLOAD = [&](int tk) {
    const size_t koff = (size_t)tk * BK;
#pragma unroll
    for (int i = 0; i < 4; ++i) {
      ra[i] = *(const uint4*)(Ag + (size_t)i * 32 * K + koff);
      rb[i] = *(const uint4*)(Bg + (size_t)i * 32 * K + koff);
    }
  };
  auto SWRITE = [&]() {
    char* p = (char*)lds;
#pragma unroll
    for (int i = 0; i < 4; ++i) {
      *(uint4*)(p + ldsoff[i])         = ra[i];
      *(uint4*)(p + 16384 + ldsoff[i]) = rb[i];
    }
  };

  f32x4 acc[4][4];
#pragma unroll
  for (int i = 0; i < 4; ++i)
#pragma unroll
    for (int j = 0; j < 4; ++j) acc[i][j] = 0.0f;

  const int l15 = lane & 15;
  const int kb0 = lane >> 4;                  // 0..3
  const int swz = (l15 & 7) << 4;
  const int arowbase = (wr * 64 + l15) * 128;
  const int browbase = (wc * 64 + l15) * 128 + 16384;

  GLOAD(0);
  SWRITE();
  for (int tk = 0; tk < NT; ++tk) {
    __syncthreads();                          // staged tile visible
    if (tk + 1 < NT) GLOAD(tk + 1);           // hide HBM latency under MFMA
    const char* p = (const char*)lds;
#pragma unroll
    for (int kh = 0; kh < 2; ++kh) {
      bf16x8 af[4], bfr[4];
      const int kby = ((kb0 + kh * 4) * 16) ^ swz;
#pragma unroll
      for (int fm = 0; fm < 4; ++fm)
        af[fm] = *(const bf16x8*)(p + arowbase + fm * 2048 + kby);
#pragma unroll
      for (int fn = 0; fn < 4; ++fn)
        bfr[fn] = *(const bf16x8*)(p + browbase + fn * 2048 + kby);
#pragma unroll
      for (int fm = 0; fm < 4; ++fm)
#pragma unroll
        for (int fn = 0; fn < 4; ++fn)
          acc[fm][fn] = __builtin_amdgcn_mfma_f32_16x16x32_bf16(
              af[fm], bfr[fn], acc[fm][fn], 0, 0, 0);
    }
    __syncthreads();                          // all reads of the tile done
    if (tk + 1 < NT) SWRITE();
  }

  const int rbase = (lane >> 4) * 4;
#pragma unroll
  for (int fn = 0; fn < 4; ++fn) {
    const int n = n0 + wc * 64 + fn * 16 + l15;
    const float bv = bias[n];
#pragma unroll
    for (int fm = 0; fm < 4; ++fm) {
      const int m = m0 + wr * 64 + fm * 16 + rbase;
      float* Cp = C + (size_t)m * N + n;
#pragma unroll
      for (int ri = 0; ri < 4; ++ri)
        Cp[(size_t)ri * N] = acc[fm][fn][ri] + bv;
    }
  }
}

// ---------------- LayerNorm (+ReLU), fp32 in, fp32 or bf16 out ------------
template<bool RELU, bool BF16OUT>
__global__ __launch_bounds__(256) void ln_act(
    const float* __restrict__ X, void* __restrict__ Y,
    const float* __restrict__ g, const float* __restrict__ be)
{
  const int t = threadIdx.x;
  const size_t base = (size_t)blockIdx.x * HID + t * 4;
  float4 v = *(const float4*)(X + base);
  float s = v.x + v.y + v.z + v.w;
  float q = v.x * v.x + v.y * v.y + v.z * v.z + v.w * v.w;
#pragma unroll
  for (int off = 32; off > 0; off >>= 1) {
    s += __shfl_down(s, off);
    q += __shfl_down(q, off);
  }
  __shared__ float ls[4], lq[4];
  if ((t & 63) == 0) { ls[t >> 6] = s; lq[t >> 6] = q; }
  __syncthreads();
  s = ls[0] + ls[1] + ls[2] + ls[3];
  q = lq[0] + lq[1] + lq[2] + lq[3];
  const float mean = s * (1.0f / HID);
  const float var  = q * (1.0f / HID) - mean * mean;
  const float rstd = rsqrtf(var + LN_EPS);
  float4 gv = *(const float4*)(g + t * 4);
  float4 bv = *(const float4*)(be + t * 4);
  float4 o;
  o.x = (v.x - mean) * rstd * gv.x + bv.x;
  o.y = (v.y - mean) * rstd * gv.y + bv.y;
  o.z = (v.z - mean) * rstd * gv.z + bv.z;
  o.w = (v.w - mean) * rstd * gv.w + bv.w;
  if (RELU) {
    o.x = fmaxf(o.x, 0.0f); o.y = fmaxf(o.y, 0.0f);
    o.z = fmaxf(o.z, 0.0f); o.w = fmaxf(o.w, 0.0f);
  }
  if (BF16OUT) {
    ushort4 u;
    u.x = f2bf(o.x); u.y = f2bf(o.y); u.z = f2bf(o.z); u.w = f2bf(o.w);
    *(ushort4*)((unsigned short*)Y + base) = u;
  } else {
    *(float4*)((float*)Y + base) = o;
  }
}

// ---------------- VQ v2: 4 rows/thread, bf16 relu(z_q) out ----------------
__global__ __launch_bounds__(256) void vq_kernel(
    const float* __restrict__ Z, const float* __restrict__ CB,
    unsigned short* __restrict__ ZQb, float* __restrict__ partial)
{
  __shared__ float e[NEMB][EDIM];   // 32 KB
  __shared__ float qn[NEMB];        // 4 KB : 0.5*|e|^2
  const int t = threadIdx.x;
  for (int i = t; i < NEMB * EDIM / 4; i += 256)
    ((float4*)&e[0][0])[i] = ((const float4*)CB)[i];
  __syncthreads();
  for (int i = t; i < NEMB; i += 256) {
    float s = 0.0f;
#pragma unroll
    for (int j = 0; j < EDIM; ++j) s += e[i][j] * e[i][j];
    qn[i] = 0.5f * s;
  }
  __syncthreads();

  constexpr int R = 4;
  size_t sv[R];
  float z[R][EDIM];
#pragma unroll
  for (int r = 0; r < R; ++r) {
    sv[r] = (size_t)blockIdx.x * 1024 + t + 256 * r;
    *(float4*)(z[r])     = *(const float4*)(Z + sv[r] * EDIM);
    *(float4*)(z[r] + 4) = *(const float4*)(Z + sv[r] * EDIM + 4);
  }

  float b1[R], b2[R];
  int   i1[R];
#pragma unroll
  for (int r = 0; r < R; ++r) { b1[r] = 1e30f; b2[r] = 1e30f; i1[r] = 0; }

  for (int i = 0; i < NEMB; i += 4) {
    const float4 qv = *(const float4*)&qn[i];
#pragma unroll
    for (int u = 0; u < 4; ++u) {
      const float4 e0 = *(const float4*)&e[i + u][0];
      const float4 e1 = *(const float4*)&e[i + u][4];
      const float q = (u == 0) ? qv.x : (u == 1) ? qv.y : (u == 2) ? qv.z : qv.w;
#pragma unroll
      for (int r = 0; r < R; ++r) {
        float d = q;
        d = fmaf(-z[r][0], e0.x, d);
        d = fmaf(-z[r][1], e0.y, d);
        d = fmaf(-z[r][2], e0.z, d);
        d = fmaf(-z[r][3], e0.w, d);
        d = fmaf(-z[r][4], e1.x, d);
        d = fmaf(-z[r][5], e1.y, d);
        d = fmaf(-z[r][6], e1.z, d);
        d = fmaf(-z[r][7], e1.w, d);
        b2[r] = fminf(b2[r], fmaxf(d, b1[r]));   // branch-free second-best
        if (d < b1[r]) { b1[r] = d; i1[r] = i + u; }
      }
    }
  }

  double lsum = 0.0;
#pragma unroll
  for (int r = 0; r < R; ++r) {
    if (b2[r] - b1[r] < 1e-4f) {      // near-tie: exact fp64 rescan (rare)
      double bd = 1e300; int ii = 0;
      for (int i = 0; i < NEMB; ++i) {
        double dd = 0.0;
#pragma unroll
        for (int j = 0; j < EDIM; ++j) {
          double diff = (double)z[r][j] - (double)e[i][j];
          dd += diff * diff;
        }
        if (dd < bd) { bd = dd; ii = i; }
      }
      i1[r] = ii;
    }
    double l = 0.0;
#pragma unroll
    for (int j = 0; j < EDIM; ++j) {
      double diff = (double)z[r][j] - (double)e[i1[r]][j];
      l += diff * diff;
    }
    lsum += l;

    float o[EDIM];
#pragma unroll
    for (int j = 0; j < EDIM; ++j) o[j] = fmaxf(e[i1[r]][j], 0.0f);
    uint4 pk;
    pk.x = (unsigned)f2bf(o[0]) | ((unsigned)f2bf(o[1]) << 16);
    pk.y = (unsigned)f2bf(o[2]) | ((unsigned)f2bf(o[3]) << 16);
    pk.z = (unsigned)f2bf(o[4]) | ((unsigned)f2bf(o[5]) << 16);
    pk.w = (unsigned)f2bf(o[6]) | ((unsigned)f2bf(o[7]) << 16);
    *(uint4*)(ZQb + sv[r] * EDIM) = pk;
  }

#pragma unroll
  for (int off = 32; off > 0; off >>= 1) lsum += __shfl_down(lsum, off);
  __shared__ double lsh[4];
  if ((t & 63) == 0) lsh[t >> 6] = lsum;
  __syncthreads();
  if (t == 0) partial[blockIdx.x] = (float)(lsh[0] + lsh[1] + lsh[2] + lsh[3]);
}

__global__ __launch_bounds__(256) void loss_finalize(
    const float* __restrict__ partial, float* __restrict__ out)
{
  const int t = threadIdx.x;
  double s = 0.0;
  for (int i = t; i < 512; i += 256) s += (double)partial[i];
#pragma unroll
  for (int off = 32; off > 0; off >>= 1) s += __shfl_down(s, off);
  __shared__ double ls[4];
  if ((t & 63) == 0) ls[t >> 6] = s;
  __syncthreads();
  if (t == 0) {
    double total = ls[0] + ls[1] + ls[2] + ls[3];
    out[0] = (float)(total * (1.0 + (double)BETA) / (double)((size_t)BATCH * HID));
  }
}

} // namespace

extern "C" void kernel_launch(void* const* d_in, const int* in_sizes, int n_in,
                              void* d_out, int out_size, void* d_ws, size_t ws_size,
                              hipStream_t stream)
{
  const float* x   = (const float*)d_in[0];
  const float* cb  = (const float*)d_in[1];
  const float* W0  = (const float*)d_in[2];
  const float* b0  = (const float*)d_in[3];
  const float* g0  = (const float*)d_in[4];
  const float* be0 = (const float*)d_in[5];
  const float* W1  = (const float*)d_in[6];
  const float* b1  = (const float*)d_in[7];
  const float* g1  = (const float*)d_in[8];
  const float* be1 = (const float*)d_in[9];
  const float* W2  = (const float*)d_in[10];
  const float* b2  = (const float*)d_in[11];
  const float* g2  = (const float*)d_in[12];
  const float* be2 = (const float*)d_in[13];
  const float* W3  = (const float*)d_in[14];
  const float* b3  = (const float*)d_in[15];
  const float* g3  = (const float*)d_in[16];
  const float* be3 = (const float*)d_in[17];
  const float* W4  = (const float*)d_in[18];
  const float* b4  = (const float*)d_in[19];
  const float* g4  = (const float*)d_in[20];
  const float* be4 = (const float*)d_in[21];
  const float* W5  = (const float*)d_in[22];
  const float* b5  = (const float*)d_in[23];
  float* out = (float*)d_out;

  char* ws = (char*)d_ws;
  constexpr size_t MB = 1024 * 1024;
  float* P = (float*)ws;                           // 16 MB region
  float* Q = (float*)(ws + 16 * MB);               // 16 MB region
  // decoder-phase overlays of the P region (encoder is done with it):
  unsigned short* Qb  = (unsigned short*)ws;       // [4096][1024] bf16, 8 MB
  unsigned short* Wt3 = (unsigned short*)(ws + 8 * MB);    // 2 MB
  unsigned short* Wt4 = (unsigned short*)(ws + 10 * MB);   // 2 MB
  unsigned short* Wt5 = (unsigned short*)(ws + 12 * MB);   // 4 MB
  float* partial = (float*)(ws + 32 * MB);         // 2 KB

  dim3 blk(256);
  dim3 gH(HID / 128, BATCH / 128);
  dim3 gO(DIN / 128, BATCH / 128);

  // encoder (fp32, unchanged numerics)
  gemm_bias_f32<<<gH, blk, 0, stream>>>(x, W0, b0, P, BATCH, HID, DIN);
  ln_act<true, false><<<dim3(BATCH), blk, 0, stream>>>(P, Q, g0, be0);
  gemm_bias_f32<<<gH, blk, 0, stream>>>(Q, W1, b1, P, BATCH, HID, HID);
  ln_act<true, false><<<dim3(BATCH), blk, 0, stream>>>(P, Q, g1, be1);
  gemm_bias_f32<<<gH, blk, 0, stream>>>(Q, W2, b2, P, BATCH, HID, HID);
  ln_act<false, false><<<dim3(BATCH), blk, 0, stream>>>(P, Q, g2, be2); // Q = z

  // decoder weight convert+transpose (P region now free above 8 MB)
  conv_w_bf16t<<<dim3(HID / 32, HID / 32), blk, 0, stream>>>(W3, Wt3, HID, HID);
  conv_w_bf16t<<<dim3(HID / 32, HID / 32), blk, 0, stream>>>(W4, Wt4, HID, HID);
  conv_w_bf16t<<<dim3(DIN / 32, HID / 32), blk, 0, stream>>>(W5, Wt5, HID, DIN);

  // vector quantize: reads z (Q), writes bf16 relu(z_q) into Qb
  vq_kernel<<<dim3(512), blk, 0, stream>>>(Q, cb, Qb, partial);

  // decoder (bf16 MFMA)
  gemm_bf16_mfma<<<gH, blk, 0, stream>>>(Qb, Wt3, b3, Q, BATCH, HID, HID);
  ln_act<true, true><<<dim3(BATCH), blk, 0, stream>>>(Q, Qb, g3, be3);
  gemm_bf16_mfma<<<gH, blk, 0, stream>>>(Qb, Wt4, b4, Q, BATCH, HID, HID);
  ln_act<true, true><<<dim3(BATCH), blk, 0, stream>>>(Q, Qb, g4, be4);
  gemm_bf16_mfma<<<gO, blk, 0, stream>>>(Qb, Wt5, b5, out, BATCH, DIN, HID);

  loss_finalize<<<dim3(1), blk, 0, stream>>>(partial, out + (size_t)BATCH * DIN);
}

// Round 6
// 975.517 us; speedup vs baseline: 1.5285x; 1.1793x over previous
//
#include <hip/hip_runtime.h>

namespace {

constexpr int BATCH = 4096;
constexpr int DIN   = 2048;
constexpr int HID   = 1024;
constexpr int NEMB  = 1024;
constexpr int EDIM  = 8;
constexpr float LN_EPS = 1e-5f;
constexpr float BETA   = 0.001f;

typedef __attribute__((ext_vector_type(8))) short bf16x8;
typedef __attribute__((ext_vector_type(4))) float f32x4;

__device__ inline unsigned short f2bf(float f) {
  unsigned int x = __float_as_uint(f);
  x += 0x7FFFu + ((x >> 16) & 1u);      // RNE
  return (unsigned short)(x >> 16);
}
__device__ inline void gl16(const void* g, void* l) {
  __builtin_amdgcn_global_load_lds(
      (const __attribute__((address_space(1))) unsigned int*)g,
      (__attribute__((address_space(3))) unsigned int*)l, 16, 0, 0);
}

// ---------------- GEMM fp32 (encoder) — R2-exact, proven numerics ---------
// 128x128 tile, BK=16, 256 threads, 8x8 micro-tile. Per-k-tile partial
// accumulators: chain ~144 (matches numpy noise scale; argmin-safe).
__global__ __launch_bounds__(256) void gemm_bias_f32(
    const float* __restrict__ A, const float* __restrict__ B,
    const float* __restrict__ bias, float* __restrict__ C,
    int M, int N, int K)
{
  constexpr int BM = 128, BN = 128, BK = 16;
  __shared__ float As[BK][BM + 4];
  __shared__ float Bs[BK][BN];
  const int t  = threadIdx.x;
  const int tx = t & 15, ty = t >> 4;
  const int bm = blockIdx.y * BM, bn = blockIdx.x * BN;

  const int a_m = t >> 1, a_k = (t & 1) << 3;
  const int b_k = t >> 4, b_n = (t & 15) << 3;

  const float* Ap = A + (size_t)(bm + a_m) * K + a_k;
  const float* Bp = B + (size_t)b_k * N + (bn + b_n);

  float acc[8][8] = {};

  for (int k0 = 0; k0 < K; k0 += BK) {
    float4 av0 = *(const float4*)(Ap + k0);
    float4 av1 = *(const float4*)(Ap + k0 + 4);
    float4 bv0 = *(const float4*)(Bp + (size_t)k0 * N);
    float4 bv1 = *(const float4*)(Bp + (size_t)k0 * N + 4);
    __syncthreads();
    As[a_k + 0][a_m] = av0.x;
    As[a_k + 1][a_m] = av0.y;
    As[a_k + 2][a_m] = av0.z;
    As[a_k + 3][a_m] = av0.w;
    As[a_k + 4][a_m] = av1.x;
    As[a_k + 5][a_m] = av1.y;
    As[a_k + 6][a_m] = av1.z;
    As[a_k + 7][a_m] = av1.w;
    *(float4*)&Bs[b_k][b_n]     = bv0;
    *(float4*)&Bs[b_k][b_n + 4] = bv1;
    __syncthreads();

    float part[8][8] = {};
#pragma unroll
    for (int k = 0; k < BK; ++k) {
      float a[8], b[8];
      *(float4*)(a)     = *(const float4*)&As[k][ty * 8];
      *(float4*)(a + 4) = *(const float4*)&As[k][ty * 8 + 4];
      *(float4*)(b)     = *(const float4*)&Bs[k][tx * 8];
      *(float4*)(b + 4) = *(const float4*)&Bs[k][tx * 8 + 4];
#pragma unroll
      for (int i = 0; i < 8; ++i)
#pragma unroll
        for (int j = 0; j < 8; ++j)
          part[i][j] = fmaf(a[i], b[j], part[i][j]);
    }
#pragma unroll
    for (int i = 0; i < 8; ++i)
#pragma unroll
      for (int j = 0; j < 8; ++j)
        acc[i][j] += part[i][j];
  }

  float bsv[8];
  *(float4*)(bsv)     = *(const float4*)(bias + bn + tx * 8);
  *(float4*)(bsv + 4) = *(const float4*)(bias + bn + tx * 8 + 4);
#pragma unroll
  for (int i = 0; i < 8; ++i) {
    float* Cr = C + (size_t)(bm + ty * 8 + i) * N + bn + tx * 8;
    float4 v0 = { acc[i][0] + bsv[0], acc[i][1] + bsv[1],
                  acc[i][2] + bsv[2], acc[i][3] + bsv[3] };
    float4 v1 = { acc[i][4] + bsv[4], acc[i][5] + bsv[5],
                  acc[i][6] + bsv[6], acc[i][7] + bsv[7] };
    *(float4*)(Cr)     = v0;
    *(float4*)(Cr + 4) = v1;
  }
}

// ---------------- GEMM bf16 MFMA (decoder): C = A @ Bt^T + bias -----------
// Structurally validated in R5 (flip-scale error, not garbage-scale).
// Tile 128x64, BK=64, 4 waves, wave-tile 64x32, 16x16x32 MFMA.
// global_load_lds w=16, linear LDS dest, pre-swizzled GLOBAL source
// (col16 ^= row&7) == read-side byte^((row&7)<<4).
__global__ __launch_bounds__(256) void gemm_mfma(
    const unsigned short* __restrict__ Ah, const unsigned short* __restrict__ Bh,
    const float* __restrict__ bias, float* __restrict__ C,
    int M, int N, int K)
{
  constexpr int BM = 128, BN = 64, BK = 64;
  __shared__ unsigned short lds[(BM + BN) * BK];        // 24 KB
  const int t = threadIdx.x, l = t & 63, w = t >> 6;
  const int wr = w >> 1, wc = w & 1;
  const int m0 = blockIdx.y * BM, n0 = blockIdx.x * BN;
  const int NT = K / BK;

  const int AHo = 0, BHo = BM * BK * 2;                 // byte offsets

  const int srow = t >> 3, scol = t & 7;
  size_t aoff[4]; int adst[4];
#pragma unroll
  for (int i = 0; i < 4; ++i) {
    int r = srow + 32 * i;
    aoff[i] = (size_t)(m0 + r) * K + ((scol ^ (r & 7)) << 3);
    adst[i] = r * 128 + scol * 16;
  }
  size_t boff[2]; int bdst[2];
#pragma unroll
  for (int i = 0; i < 2; ++i) {
    int r = srow + 32 * i;
    boff[i] = (size_t)(n0 + r) * K + ((scol ^ (r & 7)) << 3);
    bdst[i] = r * 128 + scol * 16;
  }
  char* lc = (char*)lds;

  auto GLOAD = [&](int tk) {
    const size_t k0 = (size_t)tk * BK;
#pragma unroll
    for (int i = 0; i < 4; ++i) gl16(Ah + aoff[i] + k0, lc + AHo + adst[i]);
#pragma unroll
    for (int i = 0; i < 2; ++i) gl16(Bh + boff[i] + k0, lc + BHo + bdst[i]);
  };

  f32x4 acc[4][2];
#pragma unroll
  for (int i = 0; i < 4; ++i)
#pragma unroll
    for (int j = 0; j < 2; ++j) acc[i][j] = 0.0f;

  const int l15 = l & 15, kb0 = l >> 4;
  const int swz = (l15 & 7) << 4;
  int arow[4], brow[2];
#pragma unroll
  for (int fm = 0; fm < 4; ++fm) arow[fm] = (wr * 64 + fm * 16 + l15) * 128;
#pragma unroll
  for (int fn = 0; fn < 2; ++fn) brow[fn] = (wc * 32 + fn * 16 + l15) * 128;

  GLOAD(0);
  for (int tk = 0; tk < NT; ++tk) {
    __syncthreads();                      // drains vmcnt -> tile ready
    const char* p = (const char*)lds;
#pragma unroll
    for (int kh = 0; kh < 2; ++kh) {
      const int kby = (kh * 64 + kb0 * 16) ^ swz;
      bf16x8 af[4], bf2[2];
#pragma unroll
      for (int fm = 0; fm < 4; ++fm)
        af[fm] = *(const bf16x8*)(p + AHo + arow[fm] + kby);
#pragma unroll
      for (int fn = 0; fn < 2; ++fn)
        bf2[fn] = *(const bf16x8*)(p + BHo + brow[fn] + kby);
#pragma unroll
      for (int fm = 0; fm < 4; ++fm)
#pragma unroll
        for (int fn = 0; fn < 2; ++fn)
          acc[fm][fn] = __builtin_amdgcn_mfma_f32_16x16x32_bf16(
              af[fm], bf2[fn], acc[fm][fn], 0, 0, 0);
    }
    __syncthreads();                      // all reads of the tile done
    if (tk + 1 < NT) GLOAD(tk + 1);
  }

  const int rb = (l >> 4) * 4;
#pragma unroll
  for (int fn = 0; fn < 2; ++fn) {
    const int n = n0 + wc * 32 + fn * 16 + l15;
    const float bv = bias[n];
#pragma unroll
    for (int fm = 0; fm < 4; ++fm) {
      const int m = m0 + wr * 64 + fm * 16 + rb;
      float* Cp = C + (size_t)m * N + n;
#pragma unroll
      for (int ri = 0; ri < 4; ++ri)
        Cp[(size_t)ri * N] = acc[fm][fn][ri] + bv;
    }
  }
}

// ---------------- weight convert + transpose: Wt[N][K] bf16 ---------------
__global__ __launch_bounds__(256) void conv_w_t(
    const float* __restrict__ W, unsigned short* __restrict__ Wt, int K, int N)
{
  __shared__ float tile[32][33];
  const int tx = threadIdx.x & 31, ty = threadIdx.x >> 5;
  const int n0 = blockIdx.x * 32, k0 = blockIdx.y * 32;
#pragma unroll
  for (int r = ty; r < 32; r += 8)
    tile[r][tx] = W[(size_t)(k0 + r) * N + n0 + tx];
  __syncthreads();
#pragma unroll
  for (int r = ty; r < 32; r += 8)
    Wt[(size_t)(n0 + r) * K + k0 + tx] = f2bf(tile[tx][r]);
}

// ---------------- LayerNorm (+ReLU); OM: 0=f32 out, 1=bf16 out ------------
template<bool RELU, int OM>
__global__ __launch_bounds__(256) void ln_act(
    const float* __restrict__ X, void* __restrict__ Y,
    const float* __restrict__ g, const float* __restrict__ be)
{
  const int t = threadIdx.x;
  const size_t base = (size_t)blockIdx.x * HID + t * 4;
  float4 v = *(const float4*)(X + base);
  float s = v.x + v.y + v.z + v.w;
  float q = v.x * v.x + v.y * v.y + v.z * v.z + v.w * v.w;
#pragma unroll
  for (int off = 32; off > 0; off >>= 1) {
    s += __shfl_down(s, off);
    q += __shfl_down(q, off);
  }
  __shared__ float ls[4], lq[4];
  if ((t & 63) == 0) { ls[t >> 6] = s; lq[t >> 6] = q; }
  __syncthreads();
  s = ls[0] + ls[1] + ls[2] + ls[3];
  q = lq[0] + lq[1] + lq[2] + lq[3];
  const float mean = s * (1.0f / HID);
  const float var  = q * (1.0f / HID) - mean * mean;
  const float rstd = rsqrtf(var + LN_EPS);
  float4 gv = *(const float4*)(g + t * 4);
  float4 bv = *(const float4*)(be + t * 4);
  float4 o;
  o.x = (v.x - mean) * rstd * gv.x + bv.x;
  o.y = (v.y - mean) * rstd * gv.y + bv.y;
  o.z = (v.z - mean) * rstd * gv.z + bv.z;
  o.w = (v.w - mean) * rstd * gv.w + bv.w;
  if (RELU) {
    o.x = fmaxf(o.x, 0.0f); o.y = fmaxf(o.y, 0.0f);
    o.z = fmaxf(o.z, 0.0f); o.w = fmaxf(o.w, 0.0f);
  }
  if (OM == 0) {
    *(float4*)((float*)Y + base) = o;
  } else {
    ushort4 u = { f2bf(o.x), f2bf(o.y), f2bf(o.z), f2bf(o.w) };
    *(ushort4*)((unsigned short*)Y + base) = u;
  }
}

// ---------------- VQ v3: top-2 tracking + O(1) fp64 pairwise fixup --------
__global__ __launch_bounds__(256) void vq_kernel(
    const float* __restrict__ Z, const float* __restrict__ CB,
    unsigned short* __restrict__ ZQb, float* __restrict__ partial)
{
  __shared__ float e[NEMB][EDIM];   // 32 KB
  __shared__ float qn[NEMB];        // 4 KB : 0.5*|e|^2
  const int t = threadIdx.x;
  for (int i = t; i < NEMB * EDIM / 4; i += 256)
    ((float4*)&e[0][0])[i] = ((const float4*)CB)[i];
  __syncthreads();
  for (int i = t; i < NEMB; i += 256) {
    float s = 0.0f;
#pragma unroll
    for (int j = 0; j < EDIM; ++j) s += e[i][j] * e[i][j];
    qn[i] = 0.5f * s;
  }
  __syncthreads();

  constexpr int R = 4;
  size_t sv[R];
  float z[R][EDIM];
#pragma unroll
  for (int r = 0; r < R; ++r) {
    sv[r] = (size_t)blockIdx.x * 1024 + t + 256 * r;
    *(float4*)(z[r])     = *(const float4*)(Z + sv[r] * EDIM);
    *(float4*)(z[r] + 4) = *(const float4*)(Z + sv[r] * EDIM + 4);
  }

  float b1[R], b2[R];
  int   i1[R], i2[R];
#pragma unroll
  for (int r = 0; r < R; ++r) { b1[r] = 1e30f; b2[r] = 1e30f; i1[r] = 0; i2[r] = 0; }

  for (int i = 0; i < NEMB; i += 4) {
    const float4 qv = *(const float4*)&qn[i];
#pragma unroll
    for (int u = 0; u < 4; ++u) {
      const float4 e0 = *(const float4*)&e[i + u][0];
      const float4 e1 = *(const float4*)&e[i + u][4];
      const float q = (u == 0) ? qv.x : (u == 1) ? qv.y : (u == 2) ? qv.z : qv.w;
      const int ii = i + u;
#pragma unroll
      for (int r = 0; r < R; ++r) {
        float d = q;
        d = fmaf(-z[r][0], e0.x, d);
        d = fmaf(-z[r][1], e0.y, d);
        d = fmaf(-z[r][2], e0.z, d);
        d = fmaf(-z[r][3], e0.w, d);
        d = fmaf(-z[r][4], e1.x, d);
        d = fmaf(-z[r][5], e1.y, d);
        d = fmaf(-z[r][6], e1.z, d);
        d = fmaf(-z[r][7], e1.w, d);
        const bool lt1 = d < b1[r];
        const bool lt2 = d < b2[r];
        i2[r] = lt1 ? i1[r] : (lt2 ? ii : i2[r]);
        b2[r] = fminf(fmaxf(d, b1[r]), b2[r]);   // exact 2nd-best
        if (lt1) { b1[r] = d; i1[r] = ii; }
      }
    }
  }

  double lsum = 0.0;
#pragma unroll
  for (int r = 0; r < R; ++r) {
    if (b2[r] - b1[r] < 1e-3f) {        // near-tie: exact fp64 pair compare
      double d1 = 0.0, d2 = 0.0;
#pragma unroll
      for (int j = 0; j < EDIM; ++j) {
        double f1 = (double)z[r][j] - (double)e[i1[r]][j];
        double f2 = (double)z[r][j] - (double)e[i2[r]][j];
        d1 += f1 * f1; d2 += f2 * f2;
      }
      if (d2 < d1 || (d2 == d1 && i2[r] < i1[r])) i1[r] = i2[r];
    }
    double lq = 0.0;
#pragma unroll
    for (int j = 0; j < EDIM; ++j) {
      double diff = (double)z[r][j] - (double)e[i1[r]][j];
      lq += diff * diff;
    }
    lsum += lq;

    float o[EDIM];
#pragma unroll
    for (int j = 0; j < EDIM; ++j) o[j] = fmaxf(e[i1[r]][j], 0.0f);
    uint4 pk;
    pk.x = (unsigned)f2bf(o[0]) | ((unsigned)f2bf(o[1]) << 16);
    pk.y = (unsigned)f2bf(o[2]) | ((unsigned)f2bf(o[3]) << 16);
    pk.z = (unsigned)f2bf(o[4]) | ((unsigned)f2bf(o[5]) << 16);
    pk.w = (unsigned)f2bf(o[6]) | ((unsigned)f2bf(o[7]) << 16);
    *(uint4*)(ZQb + sv[r] * EDIM) = pk;
  }

#pragma unroll
  for (int off = 32; off > 0; off >>= 1) lsum += __shfl_down(lsum, off);
  __shared__ double lsh[4];
  if ((t & 63) == 0) lsh[t >> 6] = lsum;
  __syncthreads();
  if (t == 0) partial[blockIdx.x] = (float)(lsh[0] + lsh[1] + lsh[2] + lsh[3]);
}

__global__ __launch_bounds__(256) void loss_finalize(
    const float* __restrict__ partial, float* __restrict__ out)
{
  const int t = threadIdx.x;
  double s = 0.0;
  for (int i = t; i < 512; i += 256) s += (double)partial[i];
#pragma unroll
  for (int off = 32; off > 0; off >>= 1) s += __shfl_down(s, off);
  __shared__ double ls[4];
  if ((t & 63) == 0) ls[t >> 6] = s;
  __syncthreads();
  if (t == 0) {
    double total = ls[0] + ls[1] + ls[2] + ls[3];
    out[0] = (float)(total * (1.0 + (double)BETA) / (double)((size_t)BATCH * HID));
  }
}

} // namespace

extern "C" void kernel_launch(void* const* d_in, const int* in_sizes, int n_in,
                              void* d_out, int out_size, void* d_ws, size_t ws_size,
                              hipStream_t stream)
{
  const float* x   = (const float*)d_in[0];
  const float* cb  = (const float*)d_in[1];
  const float* W0  = (const float*)d_in[2];
  const float* b0  = (const float*)d_in[3];
  const float* g0  = (const float*)d_in[4];
  const float* be0 = (const float*)d_in[5];
  const float* W1  = (const float*)d_in[6];
  const float* b1  = (const float*)d_in[7];
  const float* g1  = (const float*)d_in[8];
  const float* be1 = (const float*)d_in[9];
  const float* W2  = (const float*)d_in[10];
  const float* b2  = (const float*)d_in[11];
  const float* g2  = (const float*)d_in[12];
  const float* be2 = (const float*)d_in[13];
  const float* W3  = (const float*)d_in[14];
  const float* b3  = (const float*)d_in[15];
  const float* g3  = (const float*)d_in[16];
  const float* be3 = (const float*)d_in[17];
  const float* W4  = (const float*)d_in[18];
  const float* b4  = (const float*)d_in[19];
  const float* g4  = (const float*)d_in[20];
  const float* be4 = (const float*)d_in[21];
  const float* W5  = (const float*)d_in[22];
  const float* b5  = (const float*)d_in[23];
  float* out = (float*)d_out;

  char* ws = (char*)d_ws;
  constexpr size_t MB = 1024 * 1024;
  // ws (proven bound 32MB+8KB; max extent here 32MB+2KB):
  float* C32 = (float*)ws;                               // [0,16) GEMM out
  float* Q   = (float*)(ws + 16 * MB);                   // [16,32) fp32 acts (encoder)
  unsigned short* Qb  = (unsigned short*)(ws + 16 * MB); // [16,24) bf16 acts (decoder)
  unsigned short* W3H = (unsigned short*)(ws + 24 * MB); // [24,26) after G2
  unsigned short* W4H = (unsigned short*)(ws + 26 * MB); // [26,28)
  unsigned short* W5H = (unsigned short*)(ws + 28 * MB); // [28,32)
  float* partial = (float*)(ws + 32 * MB);               // 2 KB
  // d_out scratch: Z in upper half, dead before G5 rewrites all of d_out.
  float* Z = (float*)((char*)d_out + 16 * MB);           // [16,32)

  dim3 blk(256);
  dim3 gF32(HID / 128, BATCH / 128);   // fp32 GEMMs: (8,32)
  dim3 gDH(HID / 64, BATCH / 128);     // decoder N=1024: (16,32)
  dim3 gDO(DIN / 64, BATCH / 128);     // decoder N=2048: (32,32)

  // --- encoder (fp32 VALU, proven) ---
  gemm_bias_f32<<<gF32, blk, 0, stream>>>(x, W0, b0, C32, BATCH, HID, DIN);
  ln_act<true, 0><<<dim3(BATCH), blk, 0, stream>>>(C32, Q, g0, be0);
  gemm_bias_f32<<<gF32, blk, 0, stream>>>(Q, W1, b1, C32, BATCH, HID, HID);
  ln_act<true, 0><<<dim3(BATCH), blk, 0, stream>>>(C32, Q, g1, be1);
  gemm_bias_f32<<<gF32, blk, 0, stream>>>(Q, W2, b2, C32, BATCH, HID, HID);
  ln_act<false, 0><<<dim3(BATCH), blk, 0, stream>>>(C32, Z, g2, be2);   // z

  // --- decoder weights into [24,32) (Q dead after G2) ---
  conv_w_t<<<dim3(HID / 32, HID / 32), blk, 0, stream>>>(W3, W3H, HID, HID);
  conv_w_t<<<dim3(HID / 32, HID / 32), blk, 0, stream>>>(W4, W4H, HID, HID);
  conv_w_t<<<dim3(DIN / 32, HID / 32), blk, 0, stream>>>(W5, W5H, HID, DIN);

  // --- vector quantize: z -> bf16 relu(z_q) in Qb + loss partials ---
  vq_kernel<<<dim3(512), blk, 0, stream>>>(Z, cb, Qb, partial);

  // --- decoder (bf16 MFMA) ---
  gemm_mfma<<<gDH, blk, 0, stream>>>(Qb, W3H, b3, C32, BATCH, HID, HID);
  ln_act<true, 1><<<dim3(BATCH), blk, 0, stream>>>(C32, Qb, g3, be3);
  gemm_mfma<<<gDH, blk, 0, stream>>>(Qb, W4H, b4, C32, BATCH, HID, HID);
  ln_act<true, 1><<<dim3(BATCH), blk, 0, stream>>>(C32, Qb, g4, be4);
  gemm_mfma<<<gDO, blk, 0, stream>>>(Qb, W5H, b5, out, BATCH, DIN, HID);

  loss_finalize<<<dim3(1), blk, 0, stream>>>(partial, out + (size_t)BATCH * DIN);
}

// Round 7
// 816.764 us; speedup vs baseline: 1.8256x; 1.1944x over previous
//
#include <hip/hip_runtime.h>

namespace {

constexpr int BATCH = 4096;
constexpr int DIN   = 2048;
constexpr int HID   = 1024;
constexpr int NEMB  = 1024;
constexpr int EDIM  = 8;
constexpr float LN_EPS = 1e-5f;
constexpr float BETA   = 0.001f;

typedef __attribute__((ext_vector_type(8))) short bf16x8;
typedef __attribute__((ext_vector_type(4))) float f32x4;

__device__ inline unsigned short f2bf(float f) {
  unsigned int x = __float_as_uint(f);
  x += 0x7FFFu + ((x >> 16) & 1u);      // RNE
  return (unsigned short)(x >> 16);
}
__device__ inline void gl16(const void* g, void* l) {
  __builtin_amdgcn_global_load_lds(
      (const __attribute__((address_space(1))) unsigned int*)g,
      (__attribute__((address_space(3))) unsigned int*)l, 16, 0, 0);
}

// ---------------- GEMM fp32 split-K=2 (encoder): P[z] = A @ B over half-K --
// R2-proven body (BK=16 partial accumulators, chain ~80 per half).
// blockIdx.z selects K-half; grid 2x blocks -> 2 blocks/CU.
__global__ __launch_bounds__(256) void gemm_f32_sk(
    const float* __restrict__ A, const float* __restrict__ B,
    float* __restrict__ P, int M, int N, int K)
{
  constexpr int BM = 128, BN = 128, BK = 16;
  __shared__ float As[BK][BM + 4];
  __shared__ float Bs[BK][BN];
  const int t  = threadIdx.x;
  const int tx = t & 15, ty = t >> 4;
  const int bm = blockIdx.y * BM, bn = blockIdx.x * BN;
  const int Kh = K >> 1, kbeg = blockIdx.z * Kh;
  float* Pz = P + (size_t)blockIdx.z * M * N;

  const int a_m = t >> 1, a_k = (t & 1) << 3;
  const int b_k = t >> 4, b_n = (t & 15) << 3;

  const float* Ap = A + (size_t)(bm + a_m) * K + kbeg + a_k;
  const float* Bp = B + (size_t)(kbeg + b_k) * N + (bn + b_n);

  float acc[8][8] = {};

  for (int k0 = 0; k0 < Kh; k0 += BK) {
    float4 av0 = *(const float4*)(Ap + k0);
    float4 av1 = *(const float4*)(Ap + k0 + 4);
    float4 bv0 = *(const float4*)(Bp + (size_t)k0 * N);
    float4 bv1 = *(const float4*)(Bp + (size_t)k0 * N + 4);
    __syncthreads();
    As[a_k + 0][a_m] = av0.x;
    As[a_k + 1][a_m] = av0.y;
    As[a_k + 2][a_m] = av0.z;
    As[a_k + 3][a_m] = av0.w;
    As[a_k + 4][a_m] = av1.x;
    As[a_k + 5][a_m] = av1.y;
    As[a_k + 6][a_m] = av1.z;
    As[a_k + 7][a_m] = av1.w;
    *(float4*)&Bs[b_k][b_n]     = bv0;
    *(float4*)&Bs[b_k][b_n + 4] = bv1;
    __syncthreads();

    float part[8][8] = {};
#pragma unroll
    for (int k = 0; k < BK; ++k) {
      float a[8], b[8];
      *(float4*)(a)     = *(const float4*)&As[k][ty * 8];
      *(float4*)(a + 4) = *(const float4*)&As[k][ty * 8 + 4];
      *(float4*)(b)     = *(const float4*)&Bs[k][tx * 8];
      *(float4*)(b + 4) = *(const float4*)&Bs[k][tx * 8 + 4];
#pragma unroll
      for (int i = 0; i < 8; ++i)
#pragma unroll
        for (int j = 0; j < 8; ++j)
          part[i][j] = fmaf(a[i], b[j], part[i][j]);
    }
#pragma unroll
    for (int i = 0; i < 8; ++i)
#pragma unroll
      for (int j = 0; j < 8; ++j)
        acc[i][j] += part[i][j];
  }

#pragma unroll
  for (int i = 0; i < 8; ++i) {
    float* Pr = Pz + (size_t)(bm + ty * 8 + i) * N + bn + tx * 8;
    *(float4*)(Pr)     = *(float4*)&acc[i][0];
    *(float4*)(Pr + 4) = *(float4*)&acc[i][4];
  }
}

// ---------------- fused reduce + bias + LayerNorm (+ReLU), f32 out --------
// v = (P0 + P1) + bias, then LN. One block per row of 1024.
template<bool RELU>
__global__ __launch_bounds__(256) void ln_sk(
    const float* __restrict__ P0, const float* __restrict__ P1,
    const float* __restrict__ bias, float* __restrict__ Y,
    const float* __restrict__ g, const float* __restrict__ be)
{
  const int t = threadIdx.x;
  const size_t base = (size_t)blockIdx.x * HID + t * 4;
  float4 p0 = *(const float4*)(P0 + base);
  float4 p1 = *(const float4*)(P1 + base);
  float4 bb = *(const float4*)(bias + t * 4);
  float4 v;
  v.x = (p0.x + p1.x) + bb.x;
  v.y = (p0.y + p1.y) + bb.y;
  v.z = (p0.z + p1.z) + bb.z;
  v.w = (p0.w + p1.w) + bb.w;
  float s = v.x + v.y + v.z + v.w;
  float q = v.x * v.x + v.y * v.y + v.z * v.z + v.w * v.w;
#pragma unroll
  for (int off = 32; off > 0; off >>= 1) {
    s += __shfl_down(s, off);
    q += __shfl_down(q, off);
  }
  __shared__ float ls[4], lq[4];
  if ((t & 63) == 0) { ls[t >> 6] = s; lq[t >> 6] = q; }
  __syncthreads();
  s = ls[0] + ls[1] + ls[2] + ls[3];
  q = lq[0] + lq[1] + lq[2] + lq[3];
  const float mean = s * (1.0f / HID);
  const float var  = q * (1.0f / HID) - mean * mean;
  const float rstd = rsqrtf(var + LN_EPS);
  float4 gv = *(const float4*)(g + t * 4);
  float4 bv = *(const float4*)(be + t * 4);
  float4 o;
  o.x = (v.x - mean) * rstd * gv.x + bv.x;
  o.y = (v.y - mean) * rstd * gv.y + bv.y;
  o.z = (v.z - mean) * rstd * gv.z + bv.z;
  o.w = (v.w - mean) * rstd * gv.w + bv.w;
  if (RELU) {
    o.x = fmaxf(o.x, 0.0f); o.y = fmaxf(o.y, 0.0f);
    o.z = fmaxf(o.z, 0.0f); o.w = fmaxf(o.w, 0.0f);
  }
  *(float4*)(Y + base) = o;
}

// ---------------- GEMM bf16 MFMA (decoder) — R6-proven --------------------
__global__ __launch_bounds__(256) void gemm_mfma(
    const unsigned short* __restrict__ Ah, const unsigned short* __restrict__ Bh,
    const float* __restrict__ bias, float* __restrict__ C,
    int M, int N, int K)
{
  constexpr int BM = 128, BN = 64, BK = 64;
  __shared__ unsigned short lds[(BM + BN) * BK];        // 24 KB
  const int t = threadIdx.x, l = t & 63, w = t >> 6;
  const int wr = w >> 1, wc = w & 1;
  const int m0 = blockIdx.y * BM, n0 = blockIdx.x * BN;
  const int NT = K / BK;

  const int AHo = 0, BHo = BM * BK * 2;

  const int srow = t >> 3, scol = t & 7;
  size_t aoff[4]; int adst[4];
#pragma unroll
  for (int i = 0; i < 4; ++i) {
    int r = srow + 32 * i;
    aoff[i] = (size_t)(m0 + r) * K + ((scol ^ (r & 7)) << 3);
    adst[i] = r * 128 + scol * 16;
  }
  size_t boff[2]; int bdst[2];
#pragma unroll
  for (int i = 0; i < 2; ++i) {
    int r = srow + 32 * i;
    boff[i] = (size_t)(n0 + r) * K + ((scol ^ (r & 7)) << 3);
    bdst[i] = r * 128 + scol * 16;
  }
  char* lc = (char*)lds;

  auto GLOAD = [&](int tk) {
    const size_t k0 = (size_t)tk * BK;
#pragma unroll
    for (int i = 0; i < 4; ++i) gl16(Ah + aoff[i] + k0, lc + AHo + adst[i]);
#pragma unroll
    for (int i = 0; i < 2; ++i) gl16(Bh + boff[i] + k0, lc + BHo + bdst[i]);
  };

  f32x4 acc[4][2];
#pragma unroll
  for (int i = 0; i < 4; ++i)
#pragma unroll
    for (int j = 0; j < 2; ++j) acc[i][j] = 0.0f;

  const int l15 = l & 15, kb0 = l >> 4;
  const int swz = (l15 & 7) << 4;
  int arow[4], brow[2];
#pragma unroll
  for (int fm = 0; fm < 4; ++fm) arow[fm] = (wr * 64 + fm * 16 + l15) * 128;
#pragma unroll
  for (int fn = 0; fn < 2; ++fn) brow[fn] = (wc * 32 + fn * 16 + l15) * 128;

  GLOAD(0);
  for (int tk = 0; tk < NT; ++tk) {
    __syncthreads();
    const char* p = (const char*)lds;
#pragma unroll
    for (int kh = 0; kh < 2; ++kh) {
      const int kby = (kh * 64 + kb0 * 16) ^ swz;
      bf16x8 af[4], bf2[2];
#pragma unroll
      for (int fm = 0; fm < 4; ++fm)
        af[fm] = *(const bf16x8*)(p + AHo + arow[fm] + kby);
#pragma unroll
      for (int fn = 0; fn < 2; ++fn)
        bf2[fn] = *(const bf16x8*)(p + BHo + brow[fn] + kby);
#pragma unroll
      for (int fm = 0; fm < 4; ++fm)
#pragma unroll
        for (int fn = 0; fn < 2; ++fn)
          acc[fm][fn] = __builtin_amdgcn_mfma_f32_16x16x32_bf16(
              af[fm], bf2[fn], acc[fm][fn], 0, 0, 0);
    }
    __syncthreads();
    if (tk + 1 < NT) GLOAD(tk + 1);
  }

  const int rb = (l >> 4) * 4;
#pragma unroll
  for (int fn = 0; fn < 2; ++fn) {
    const int n = n0 + wc * 32 + fn * 16 + l15;
    const float bv = bias[n];
#pragma unroll
    for (int fm = 0; fm < 4; ++fm) {
      const int m = m0 + wr * 64 + fm * 16 + rb;
      float* Cp = C + (size_t)m * N + n;
#pragma unroll
      for (int ri = 0; ri < 4; ++ri)
        Cp[(size_t)ri * N] = acc[fm][fn][ri] + bv;
    }
  }
}

// ---------------- weight convert + transpose: Wt[N][K] bf16 ---------------
__global__ __launch_bounds__(256) void conv_w_t(
    const float* __restrict__ W, unsigned short* __restrict__ Wt, int K, int N)
{
  __shared__ float tile[32][33];
  const int tx = threadIdx.x & 31, ty = threadIdx.x >> 5;
  const int n0 = blockIdx.x * 32, k0 = blockIdx.y * 32;
#pragma unroll
  for (int r = ty; r < 32; r += 8)
    tile[r][tx] = W[(size_t)(k0 + r) * N + n0 + tx];
  __syncthreads();
#pragma unroll
  for (int r = ty; r < 32; r += 8)
    Wt[(size_t)(n0 + r) * K + k0 + tx] = f2bf(tile[tx][r]);
}

// ---------------- LayerNorm (+ReLU), f32 in, bf16 out (decoder) -----------
template<bool RELU>
__global__ __launch_bounds__(256) void ln_act(
    const float* __restrict__ X, unsigned short* __restrict__ Y,
    const float* __restrict__ g, const float* __restrict__ be)
{
  const int t = threadIdx.x;
  const size_t base = (size_t)blockIdx.x * HID + t * 4;
  float4 v = *(const float4*)(X + base);
  float s = v.x + v.y + v.z + v.w;
  float q = v.x * v.x + v.y * v.y + v.z * v.z + v.w * v.w;
#pragma unroll
  for (int off = 32; off > 0; off >>= 1) {
    s += __shfl_down(s, off);
    q += __shfl_down(q, off);
  }
  __shared__ float ls[4], lq[4];
  if ((t & 63) == 0) { ls[t >> 6] = s; lq[t >> 6] = q; }
  __syncthreads();
  s = ls[0] + ls[1] + ls[2] + ls[3];
  q = lq[0] + lq[1] + lq[2] + lq[3];
  const float mean = s * (1.0f / HID);
  const float var  = q * (1.0f / HID) - mean * mean;
  const float rstd = rsqrtf(var + LN_EPS);
  float4 gv = *(const float4*)(g + t * 4);
  float4 bv = *(const float4*)(be + t * 4);
  float4 o;
  o.x = (v.x - mean) * rstd * gv.x + bv.x;
  o.y = (v.y - mean) * rstd * gv.y + bv.y;
  o.z = (v.z - mean) * rstd * gv.z + bv.z;
  o.w = (v.w - mean) * rstd * gv.w + bv.w;
  if (RELU) {
    o.x = fmaxf(o.x, 0.0f); o.y = fmaxf(o.y, 0.0f);
    o.z = fmaxf(o.z, 0.0f); o.w = fmaxf(o.w, 0.0f);
  }
  ushort4 u = { f2bf(o.x), f2bf(o.y), f2bf(o.z), f2bf(o.w) };
  *(ushort4*)(Y + base) = u;
}

// ---------------- VQ v4: R=2 rows/thread, grid 1024 (occupancy fix) -------
__global__ __launch_bounds__(256) void vq_kernel(
    const float* __restrict__ Z, const float* __restrict__ CB,
    unsigned short* __restrict__ ZQb, float* __restrict__ partial)
{
  __shared__ float e[NEMB][EDIM];   // 32 KB
  __shared__ float qn[NEMB];        // 4 KB : 0.5*|e|^2
  const int t = threadIdx.x;
  for (int i = t; i < NEMB * EDIM / 4; i += 256)
    ((float4*)&e[0][0])[i] = ((const float4*)CB)[i];
  __syncthreads();
  for (int i = t; i < NEMB; i += 256) {
    float s = 0.0f;
#pragma unroll
    for (int j = 0; j < EDIM; ++j) s += e[i][j] * e[i][j];
    qn[i] = 0.5f * s;
  }
  __syncthreads();

  constexpr int R = 2;
  size_t sv[R];
  float z[R][EDIM];
#pragma unroll
  for (int r = 0; r < R; ++r) {
    sv[r] = (size_t)blockIdx.x * 512 + t + 256 * r;
    *(float4*)(z[r])     = *(const float4*)(Z + sv[r] * EDIM);
    *(float4*)(z[r] + 4) = *(const float4*)(Z + sv[r] * EDIM + 4);
  }

  float b1[R], b2[R];
  int   i1[R], i2[R];
#pragma unroll
  for (int r = 0; r < R; ++r) { b1[r] = 1e30f; b2[r] = 1e30f; i1[r] = 0; i2[r] = 0; }

  for (int i = 0; i < NEMB; i += 4) {
    const float4 qv = *(const float4*)&qn[i];
#pragma unroll
    for (int u = 0; u < 4; ++u) {
      const float4 e0 = *(const float4*)&e[i + u][0];
      const float4 e1 = *(const float4*)&e[i + u][4];
      const float q = (u == 0) ? qv.x : (u == 1) ? qv.y : (u == 2) ? qv.z : qv.w;
      const int ii = i + u;
#pragma unroll
      for (int r = 0; r < R; ++r) {
        float d = q;
        d = fmaf(-z[r][0], e0.x, d);
        d = fmaf(-z[r][1], e0.y, d);
        d = fmaf(-z[r][2], e0.z, d);
        d = fmaf(-z[r][3], e0.w, d);
        d = fmaf(-z[r][4], e1.x, d);
        d = fmaf(-z[r][5], e1.y, d);
        d = fmaf(-z[r][6], e1.z, d);
        d = fmaf(-z[r][7], e1.w, d);
        const bool lt1 = d < b1[r];
        const bool lt2 = d < b2[r];
        i2[r] = lt1 ? i1[r] : (lt2 ? ii : i2[r]);
        b2[r] = fminf(fmaxf(d, b1[r]), b2[r]);   // exact 2nd-best
        if (lt1) { b1[r] = d; i1[r] = ii; }
      }
    }
  }

  double lsum = 0.0;
#pragma unroll
  for (int r = 0; r < R; ++r) {
    if (b2[r] - b1[r] < 1e-3f) {        // near-tie: exact fp64 pair compare
      double d1 = 0.0, d2 = 0.0;
#pragma unroll
      for (int j = 0; j < EDIM; ++j) {
        double f1 = (double)z[r][j] - (double)e[i1[r]][j];
        double f2 = (double)z[r][j] - (double)e[i2[r]][j];
        d1 += f1 * f1; d2 += f2 * f2;
      }
      if (d2 < d1 || (d2 == d1 && i2[r] < i1[r])) i1[r] = i2[r];
    }
    double lq = 0.0;
#pragma unroll
    for (int j = 0; j < EDIM; ++j) {
      double diff = (double)z[r][j] - (double)e[i1[r]][j];
      lq += diff * diff;
    }
    lsum += lq;

    float o[EDIM];
#pragma unroll
    for (int j = 0; j < EDIM; ++j) o[j] = fmaxf(e[i1[r]][j], 0.0f);
    uint4 pk;
    pk.x = (unsigned)f2bf(o[0]) | ((unsigned)f2bf(o[1]) << 16);
    pk.y = (unsigned)f2bf(o[2]) | ((unsigned)f2bf(o[3]) << 16);
    pk.z = (unsigned)f2bf(o[4]) | ((unsigned)f2bf(o[5]) << 16);
    pk.w = (unsigned)f2bf(o[6]) | ((unsigned)f2bf(o[7]) << 16);
    *(uint4*)(ZQb + sv[r] * EDIM) = pk;
  }

#pragma unroll
  for (int off = 32; off > 0; off >>= 1) lsum += __shfl_down(lsum, off);
  __shared__ double lsh[4];
  if ((t & 63) == 0) lsh[t >> 6] = lsum;
  __syncthreads();
  if (t == 0) partial[blockIdx.x] = (float)(lsh[0] + lsh[1] + lsh[2] + lsh[3]);
}

__global__ __launch_bounds__(256) void loss_finalize(
    const float* __restrict__ partial, float* __restrict__ out)
{
  const int t = threadIdx.x;
  double s = 0.0;
  for (int i = t; i < 1024; i += 256) s += (double)partial[i];
#pragma unroll
  for (int off = 32; off > 0; off >>= 1) s += __shfl_down(s, off);
  __shared__ double ls[4];
  if ((t & 63) == 0) ls[t >> 6] = s;
  __syncthreads();
  if (t == 0) {
    double total = ls[0] + ls[1] + ls[2] + ls[3];
    out[0] = (float)(total * (1.0 + (double)BETA) / (double)((size_t)BATCH * HID));
  }
}

} // namespace

extern "C" void kernel_launch(void* const* d_in, const int* in_sizes, int n_in,
                              void* d_out, int out_size, void* d_ws, size_t ws_size,
                              hipStream_t stream)
{
  const float* x   = (const float*)d_in[0];
  const float* cb  = (const float*)d_in[1];
  const float* W0  = (const float*)d_in[2];
  const float* b0  = (const float*)d_in[3];
  const float* g0  = (const float*)d_in[4];
  const float* be0 = (const float*)d_in[5];
  const float* W1  = (const float*)d_in[6];
  const float* b1  = (const float*)d_in[7];
  const float* g1  = (const float*)d_in[8];
  const float* be1 = (const float*)d_in[9];
  const float* W2  = (const float*)d_in[10];
  const float* b2  = (const float*)d_in[11];
  const float* g2  = (const float*)d_in[12];
  const float* be2 = (const float*)d_in[13];
  const float* W3  = (const float*)d_in[14];
  const float* b3  = (const float*)d_in[15];
  const float* g3  = (const float*)d_in[16];
  const float* be3 = (const float*)d_in[17];
  const float* W4  = (const float*)d_in[18];
  const float* b4  = (const float*)d_in[19];
  const float* g4  = (const float*)d_in[20];
  const float* be4 = (const float*)d_in[21];
  const float* W5  = (const float*)d_in[22];
  const float* b5  = (const float*)d_in[23];
  float* out = (float*)d_out;

  char* ws = (char*)d_ws;
  constexpr size_t MB = 1024 * 1024;
  // ws (proven bound 32MB+8KB; max extent here 32MB+4KB):
  float* C32 = (float*)ws;                               // [0,16) decoder GEMM out
  float* Q   = (float*)(ws + 16 * MB);                   // [16,32) fp32 acts (encoder)
  unsigned short* Qb  = (unsigned short*)(ws + 16 * MB); // [16,24) bf16 acts (decoder)
  unsigned short* W3H = (unsigned short*)(ws + 24 * MB); // [24,26)
  unsigned short* W4H = (unsigned short*)(ws + 26 * MB); // [26,28)
  unsigned short* W5H = (unsigned short*)(ws + 28 * MB); // [28,32)
  float* partial = (float*)(ws + 32 * MB);               // 4 KB
  // d_out (32MB) as scratch during encoder: split-K partials P0/P1; then Z.
  float* P0 = (float*)d_out;                             // [0,16)
  float* P1 = (float*)((char*)d_out + 16 * MB);          // [16,32)
  float* Z  = (float*)((char*)d_out + 16 * MB);          // [16,32) after G2-LN
                                                         // (in-place over P1, addr-exact)

  dim3 blk(256);
  dim3 gSK(HID / 128, BATCH / 128, 2);  // split-K fp32 GEMMs: 512 blocks
  dim3 gDH(HID / 64, BATCH / 128);      // decoder N=1024: 512 blocks
  dim3 gDO(DIN / 64, BATCH / 128);      // decoder N=2048: 1024 blocks

  // --- encoder (fp32 split-K=2 + fused reduce/bias/LN) ---
  gemm_f32_sk<<<gSK, blk, 0, stream>>>(x, W0, P0, BATCH, HID, DIN);
  ln_sk<true><<<dim3(BATCH), blk, 0, stream>>>(P0, P1, b0, Q, g0, be0);
  gemm_f32_sk<<<gSK, blk, 0, stream>>>(Q, W1, P0, BATCH, HID, HID);
  ln_sk<true><<<dim3(BATCH), blk, 0, stream>>>(P0, P1, b1, Q, g1, be1);
  gemm_f32_sk<<<gSK, blk, 0, stream>>>(Q, W2, P0, BATCH, HID, HID);
  ln_sk<false><<<dim3(BATCH), blk, 0, stream>>>(P0, P1, b2, Z, g2, be2);  // z (in-place)

  // --- decoder weights into [24,32) (Q dead after G2) ---
  conv_w_t<<<dim3(HID / 32, HID / 32), blk, 0, stream>>>(W3, W3H, HID, HID);
  conv_w_t<<<dim3(HID / 32, HID / 32), blk, 0, stream>>>(W4, W4H, HID, HID);
  conv_w_t<<<dim3(DIN / 32, HID / 32), blk, 0, stream>>>(W5, W5H, HID, DIN);

  // --- vector quantize: z -> bf16 relu(z_q) in Qb + loss partials ---
  vq_kernel<<<dim3(1024), blk, 0, stream>>>(Z, cb, Qb, partial);

  // --- decoder (bf16 MFMA) ---
  gemm_mfma<<<gDH, blk, 0, stream>>>(Qb, W3H, b3, C32, BATCH, HID, HID);
  ln_act<true><<<dim3(BATCH), blk, 0, stream>>>(C32, Qb, g3, be3);
  gemm_mfma<<<gDH, blk, 0, stream>>>(Qb, W4H, b4, C32, BATCH, HID, HID);
  ln_act<true><<<dim3(BATCH), blk, 0, stream>>>(C32, Qb, g4, be4);
  gemm_mfma<<<gDO, blk, 0, stream>>>(Qb, W5H, b5, out, BATCH, DIN, HID);

  loss_finalize<<<dim3(1), blk, 0, stream>>>(partial, out + (size_t)BATCH * DIN);
}